// Round 7
// baseline (118.608 us; speedup 1.0000x reference)
//
#include <hip/hip_runtime.h>
#include <cstdint>
#include <cstddef>

// Problem: B=8, C=64, H=W=32 -> N=8192 nodes, K=9 neighbors, OUT=64.
// Batches: k = [1024k,1024(k+1)) for k<=6, batch 7 = [7168,8190], batch 8 = {8191}.
// Node g: b = g>>10, hw = g&1023; feature ch of g = x[b*65536 + ch*1024 + hw].
//
// R7: ONE fused kernel (no D matrix, no inter-kernel gaps).
// Block = 32 rows (grid 256 = 1 block/CU). Wave owns 8 rows.
// Lane l owns candidates c = 4l + 256e + j  (e=0..3, j=0..3 -> 16 slots).
// Phase 1: stream 64 channels; cands via coalesced global f4 (L1/L2-hot),
//          rows via readlane from regs; acc[8][16] fp32 dots + sqc[16];
//          side-write bf16 cand copy to LDS [64][1028] (quarter per wave).
// Phase 2: per row: dists from regs -> 32-bit tournament top-9 (exact
//          reference tie-break: min dist, then min index); winner's features
//          accumulated from LDS bf16 immediately (no index array).
// Phase 3: out = mean@Wl^T + bl + self@Wr^T; W in per-lane regs; means/self
//          broadcast via readlane. Self term fully fp32.

#define CBUF_HW (64 * 1028)          // ushort count
#define CBUF_BYTES (CBUF_HW * 2)     // 131,584 B dynamic LDS

__device__ __forceinline__ unsigned mono32(float d) {
  unsigned u = __float_as_uint(d);
  return (u & 0x80000000u) ? ~u : (u | 0x80000000u);
}

__device__ __forceinline__ unsigned bmin32(unsigned v) {
#pragma unroll
  for (int off = 32; off; off >>= 1) {
    unsigned o = (unsigned)__shfl_xor((int)v, off, 64);
    v = (o < v) ? o : v;
  }
  return v;
}

__device__ __forceinline__ float rdlane(float v, int src) {
  return __int_as_float(__builtin_amdgcn_readlane(__float_as_int(v), src));
}

__device__ __forceinline__ unsigned short bf16rn(float v) {
  unsigned bits = __float_as_uint(v);
  return (unsigned short)((bits + 0x7FFFu + ((bits >> 16) & 1u)) >> 16);
}

extern "C" __global__ __launch_bounds__(256, 1)
void k_fused(const float* __restrict__ x,
             const float* __restrict__ Wl,
             const float* __restrict__ bl,
             const float* __restrict__ Wr,
             float* __restrict__ out) {
  extern __shared__ unsigned short cbuf[];   // [64][1028] bf16
  int t = threadIdx.x;
  int lane = t & 63;
  int w = t >> 6;
  int n0 = (int)blockIdx.x << 5;             // 32 rows per block
  int s = (n0 >= 7168) ? 7168 : (n0 & ~1023);
  int b = s >> 10;
  const float* xb = x + ((size_t)b << 16);

  // self features: lane = channel (8 scattered loads, once)
  float rowf[8];
#pragma unroll
  for (int r = 0; r < 8; ++r) {
    int n = n0 + (w << 3) + r;
    rowf[r] = xb[(lane << 10) + (n & 1023)];
  }

  float acc[8][16];
#pragma unroll
  for (int r = 0; r < 8; ++r)
#pragma unroll
    for (int q = 0; q < 16; ++q) acc[r][q] = 0.f;
  float sqc[16];
#pragma unroll
  for (int q = 0; q < 16; ++q) sqc[q] = 0.f;

  // -------- phase 1: channel stream --------
  float4 cnd[2][4];
#pragma unroll
  for (int e = 0; e < 4; ++e)
    cnd[0][e] = *(const float4*)&xb[(lane << 2) + (e << 8)];  // ch 0

#pragma unroll 1
  for (int ch2 = 0; ch2 < 32; ++ch2) {
#pragma unroll
    for (int h = 0; h < 2; ++h) {
      int ch = (ch2 << 1) + h;
      int cur = ch & 1;
      if ((ch & 7) == 0) __syncthreads();    // keep waves L1-aligned
      int chn = (ch < 63) ? ch + 1 : 63;
#pragma unroll
      for (int e = 0; e < 4; ++e)
        cnd[cur ^ 1][e] = *(const float4*)&xb[(chn << 10) + (lane << 2) + (e << 8)];
      // bf16 side-copy: wave w owns channels [16w, 16w+16)
      if ((ch >> 4) == w) {
#pragma unroll
        for (int e = 0; e < 4; ++e) {
          ushort4 pk;
          pk.x = bf16rn(cnd[cur][e].x);
          pk.y = bf16rn(cnd[cur][e].y);
          pk.z = bf16rn(cnd[cur][e].z);
          pk.w = bf16rn(cnd[cur][e].w);
          *(ushort4*)&cbuf[ch * 1028 + (lane << 2) + (e << 8)] = pk;
        }
      }
      float rv[8];
#pragma unroll
      for (int r = 0; r < 8; ++r) rv[r] = rdlane(rowf[r], ch);
#pragma unroll
      for (int e = 0; e < 4; ++e) {
        float cv[4] = {cnd[cur][e].x, cnd[cur][e].y, cnd[cur][e].z, cnd[cur][e].w};
#pragma unroll
        for (int j = 0; j < 4; ++j) {
          int q = (e << 2) + j;
          sqc[q] = fmaf(cv[j], cv[j], sqc[q]);
#pragma unroll
          for (int r = 0; r < 8; ++r)
            acc[r][q] = fmaf(rv[r], cv[j], acc[r][q]);
        }
      }
    }
  }
  __syncthreads();                           // cbuf complete

  // -------- phase 2: per-row top-9 + bf16 mean accumulation --------
  float ms[8];
#pragma unroll
  for (int r = 0; r < 8; ++r) {
    int n = n0 + (w << 3) + r;
    if (n == 8191) { ms[r] = rowf[r]; continue; }   // singleton batch: self
    int lr = n - s;
    // this row's sq: owner lane/slot of cand c = lr
    int lslot = (((lr >> 8) << 2) | (lr & 3));
    int llane = (lr >> 2) & 63;
    float sel = sqc[0];
#pragma unroll
    for (int q = 1; q < 16; ++q) sel = (q == lslot) ? sqc[q] : sel;
    float sqr = __shfl(sel, llane, 64);

    bool mrow = (s == 7168);                 // exclude cand c=1023 (node 8191)
    unsigned d[16];
#pragma unroll
    for (int q = 0; q < 16; ++q)
      d[q] = mono32((sqr + sqc[q]) - 2.f * acc[r][q]);
    if (mrow && lane == 63) d[15] = 0xFFFFFFFFu;

    // per-lane cached top-2 (strict < keeps earliest slot = smallest c)
    unsigned m1d = d[0], m2d = d[1];
    int m1s = 0, m2s = 1;
    if (m2d < m1d) { unsigned td = m1d; m1d = m2d; m2d = td; m1s = 1; m2s = 0; }
#pragma unroll
    for (int q = 2; q < 16; ++q) {
      unsigned dq = d[q];
      bool lt1 = dq < m1d, lt2 = dq < m2d;
      m2d = lt1 ? m1d : (lt2 ? dq : m2d);
      m2s = lt1 ? m1s : (lt2 ? q : m2s);
      m1d = lt1 ? dq : m1d;
      m1s = lt1 ? q : m1s;
    }
    unsigned lmd = m1d;
    int lms = m1s;
    unsigned rmask = 0;
    bool stale = false;
    float msum = 0.f;
#pragma unroll 1
    for (int kk = 0; kk < 9; ++kk) {
      unsigned g = bmin32(lmd);
      bool eq = (lmd == g);
      unsigned long long mask = __ballot(eq);
      unsigned cc = ((unsigned)lane << 2) | ((unsigned)(lms >> 2) << 8) | (unsigned)(lms & 3);
      unsigned wc;
      if (__popcll(mask) == 1) {             // unique min dist (common)
        wc = (unsigned)__shfl((int)cc, (int)(__ffsll((long long)mask) - 1), 64);
      } else {                               // exact fp tie: min index
        unsigned tc = eq ? cc : 0xFFFFFFFFu;
        wc = bmin32(tc);
      }
      // accumulate winner's feature (lane = channel) from bf16 LDS copy
      msum += __uint_as_float((unsigned)cbuf[lane * 1028 + (int)wc] << 16);
      if (eq && cc == wc) {                  // this lane consumed its min
        rmask |= 1u << lms;
        if (!stale) { lmd = m2d; lms = m2s; stale = true; }
        else {
          unsigned bd = 0xFFFFFFFFu; int bs = 0;
#pragma unroll
          for (int q = 0; q < 16; ++q) {
            bool alive = ((rmask >> q) & 1u) == 0u;
            bool take = alive && (d[q] < bd);
            bd = take ? d[q] : bd;
            bs = take ? q : bs;
          }
          lmd = bd; lms = bs;
        }
      }
    }
    ms[r] = msum / 9.0f;
  }

  // -------- phase 3: out = mean@Wl^T + bl + self@Wr^T (lane = out ch) --------
  float4 wl4[16], wr4[16];
#pragma unroll
  for (int k = 0; k < 16; ++k) {
    wl4[k] = *(const float4*)&Wl[(lane << 6) + (k << 2)];
    wr4[k] = *(const float4*)&Wr[(lane << 6) + (k << 2)];
  }
  float bias = bl[lane];
#pragma unroll 1
  for (int r = 0; r < 8; ++r) {
    int n = n0 + (w << 3) + r;
    float accL = 0.f, accR = 0.f;
#pragma unroll
    for (int c = 0; c < 64; ++c) {
      float mc = rdlane(ms[r], c);
      float xc = rdlane(rowf[r], c);
      const float* wlp = (const float*)&wl4[c >> 2];
      const float* wrp = (const float*)&wr4[c >> 2];
      accL = fmaf(mc, wlp[c & 3], accL);
      accR = fmaf(xc, wrp[c & 3], accR);
    }
    out[((size_t)n << 6) + lane] = accL + accR + bias;
  }
}

// ---------------------------------------------------------------------------
extern "C" void kernel_launch(void* const* d_in, const int* in_sizes, int n_in,
                              void* d_out, int out_size, void* d_ws, size_t ws_size,
                              hipStream_t stream) {
  const float* x  = (const float*)d_in[0];   // (8,64,32,32)
  const float* Wl = (const float*)d_in[1];   // (64,64)
  const float* bl = (const float*)d_in[2];   // (64,)
  const float* Wr = (const float*)d_in[3];   // (64,64)
  float* out = (float*)d_out;                // (8192,64)

  // dynamic LDS > 64 KB: opt in every call (idempotent, capture-safe)
  hipFuncSetAttribute((const void*)k_fused,
                      hipFuncAttributeMaxDynamicSharedMemorySize, CBUF_BYTES);
  k_fused<<<256, 256, CBUF_BYTES, stream>>>(x, Wl, bl, Wr, out);
}